// Round 9
// baseline (733.103 us; speedup 1.0000x reference)
//
#include <hip/hip_runtime.h>
#include <hip/hip_bf16.h>

#define NROWS 8192
#define DDIM 768

typedef short short8 __attribute__((ext_vector_type(8)));   // 8 x bf16 (4 VGPRs)
typedef float floatx4 __attribute__((ext_vector_type(4)));  // MFMA C/D
typedef float f4 __attribute__((ext_vector_type(4)));
#define TSTRIDE2 260  // mirror transpose LDS row stride (floats)

// slab schedule: 128 slabs over 24 iters, compile-time
#define SLB(k) (((k) * 128) / 24)

// ---------------------------------------------------------------------------
// Kernel 1: row-normalize features (fp32 in) -> bf16 normalized rows
// ---------------------------------------------------------------------------
__global__ __launch_bounds__(256) void normalize_k(const float* __restrict__ f,
                                                   __hip_bfloat16* __restrict__ fn) {
    const int row = blockIdx.x;
    const int t = threadIdx.x;
    const float* fr = f + (size_t)row * DDIM;
    float v0 = fr[t];
    float v1 = fr[t + 256];
    float v2 = fr[t + 512];
    float ss = v0 * v0 + v1 * v1 + v2 * v2;
#pragma unroll
    for (int m = 32; m; m >>= 1) ss += __shfl_xor(ss, m, 64);
    __shared__ float wsum[4];
    if ((t & 63) == 0) wsum[t >> 6] = ss;
    __syncthreads();
    float tot = wsum[0] + wsum[1] + wsum[2] + wsum[3];
    float inv = 1.0f / fmaxf(sqrtf(tot), 1e-8f);
    __hip_bfloat16* o = fn + (size_t)row * DDIM;
    o[t]       = __float2bfloat16(v0 * inv);
    o[t + 256] = __float2bfloat16(v1 * inv);
    o[t + 512] = __float2bfloat16(v2 * inv);
}

// ---------------------------------------------------------------------------
// Kernel 2: SYMMETRIC bf16 GEMM (s = 10 * fn fn^T) + fused mask reductions.
// R17: 256x256 tile. Evidence across R8/R15/R16 (three structures, occupancy
// 38/29/20%, all ~195-215 us): wall time ~= total vmem bytes / ~6.9 TB/s
// system delivery (masks 537 MB HBM + fn 818 MB L3). Scheduling is +-3%;
// BYTES are the pacer. 256^2 halves fn traffic (818->409 MB) -> ~140-155 us.
// 528 blocks x 512 threads, LDS 128 KB (fn 32K single-buf + 12x8KB slabs).
// Mask streaming machinery identical in spirit to R14/R15 (HW-verified):
// depth-1 slab prefetch, counted vmcnt (simulated: prologue m(0){5}; per
// iter issue fn{4}+m(kt+1){c}; wait vmcnt(c(kt+1)), c = 5 or 6 (6 iff
// kt%3==1), iter23 -> 0); fma-nibble pack; packer==consumer (re-derived for
// 256^2: direct owner wn==rg>>4 && cl>>3==rg&1, nf=(rg>>1)&7; mirror owner
// t>>7==rg&3, st=rg>>2); slab slot s%12, reuse spacing >=2 iters.
// ---------------------------------------------------------------------------
__global__ __launch_bounds__(512, 2) void ntxent_main(
        const __hip_bfloat16* __restrict__ fn,
        const float* __restrict__ pmask, const float* __restrict__ nmask,
        float* __restrict__ negG, float* __restrict__ sG,
        float* __restrict__ pG) {
    __shared__ __align__(16) char smem[131072];  // fn 32K | 12 mask slots 96K
    char* IsB = smem;                            // 256 rows x 64B
    char* JsB = smem + 16384;
    char* maskLds = smem + 32768;                // 12 x 8192
    float* T = (float*)smem;                     // mirror transpose alias (epilogue)

    const int t = threadIdx.x;
    const int lane = t & 63;
    const int wv = t >> 6;          // 0..7
    const int wn = wv & 1;          // i-half (128 rows)
    const int wm = wv >> 1;         // j-quarter (64 cols)
    const int q  = lane >> 4;
    const int cl = lane & 15;

    // XCD-chunked swizzle (528 = 8*66, bijective)
    const int bt0 = blockIdx.x;
    const int bt = (bt0 & 7) * 66 + (bt0 >> 3);

    // triangular decode: block bt -> (c, r) with c <= r   (32 tiles)
    int r = (int)((sqrtf(8.0f * (float)bt + 1.0f) - 1.0f) * 0.5f);
    while ((r + 1) * (r + 2) / 2 <= bt) ++r;
    while (r * (r + 1) / 2 > bt) --r;
    const int c = bt - r * (r + 1) / 2;
    const int rowBase = c * 256;     // i-tile
    const int colBase = r * 256;     // j-tile
    const bool offDiag = (c != r);

    const int rdSw = ((q ^ ((cl >> 1) & 3)) << 4);

    // slab DMA per-thread constants: row in slab (8), source-swizzled quad (64)
    const int sRow = t >> 6;                        // 0..7
    const int sChunk = (t & 63) ^ (sRow & 7);       // source quad (pre-swizzled)

    floatx4 acc[4][8];            // [mf (j)][nf (i)]
#pragma unroll
    for (int mf = 0; mf < 4; ++mf)
#pragma unroll
        for (int nf = 0; nf < 8; ++nf)
            acc[mf][nf] = (floatx4){0.f, 0.f, 0.f, 0.f};

    // packed mask words: direct per nf, mirror per st; bits [15:0]=pos [31:16]=neg
    unsigned int dw[8] = {0u,0u,0u,0u,0u,0u,0u,0u};
    unsigned int mw[8] = {0u,0u,0u,0u,0u,0u,0u,0u};

    // slab s in [0,128): side=s>>6 (0 direct,1 mirror), h=s&63, rg=h>>1, isN=h&1
    auto issue_slab = [&](int s) {
        const int slot = s % 12;
        const int side = s >> 6;
        const int rg   = (s & 63) >> 1;
        const float* mp = (s & 1) ? nmask : pmask;
        const int rowG = (side ? colBase : rowBase) + rg * 8 + sRow;
        const int colG = (side ? rowBase : colBase) + sChunk * 4;
        const float* src = mp + (size_t)rowG * NROWS + colG;
        __builtin_amdgcn_global_load_lds(
            (const __attribute__((address_space(1))) void*)src,
            (__attribute__((address_space(3))) void*)(maskLds + slot * 8192 + t * 16),
            16, 0, 0);
    };

    // fn staging for K-step k0 (single buffer): 4 x global_load_lds
    auto issue_fn = [&](int k0) {
#pragma unroll
        for (int it = 0; it < 2; ++it) {
            const int s = it * 512 + t;              // 16B slot 0..1023
            const int rr = s >> 2;                   // 0..255
            const int cg = (s & 3) ^ ((rr >> 1) & 3);
            const __hip_bfloat16* ga = fn + (size_t)(rowBase + rr) * DDIM + k0 + cg * 8;
            const __hip_bfloat16* gb = fn + (size_t)(colBase + rr) * DDIM + k0 + cg * 8;
            __builtin_amdgcn_global_load_lds(
                (const __attribute__((address_space(1))) void*)ga,
                (__attribute__((address_space(3))) void*)(IsB + s * 16), 16, 0, 0);
            __builtin_amdgcn_global_load_lds(
                (const __attribute__((address_space(1))) void*)gb,
                (__attribute__((address_space(3))) void*)(JsB + s * 16), 16, 0, 0);
        }
    };

    // pack: nibble = m0+2m1+4m2+8m3 (exact 0/1); word = sum 16^mf * nib
    auto pack_slab = [&](int s) {
        const int slot = s % 12;
        const int side = s >> 6;
        const int rg   = (s & 63) >> 1;
        const int sh   = (s & 1) ? 16 : 0;
        if (side == 0) {
            if (wn == ((rg >> 4) & 1) && (cl >> 3) == (rg & 1)) {
                const int nf = (rg >> 1) & 7;
                const int rl = cl & 7;
                const char* base = maskLds + slot * 8192 + rl * 1024;
                float word = 0.f;
#pragma unroll
                for (int mf = 3; mf >= 0; --mf) {
                    const int pos = (wm * 16 + mf * 4 + q) ^ rl;
                    const f4 m = *(const f4*)(base + pos * 16);
                    float nib = fmaf(2.f, m[1], m[0]) + fmaf(8.f, m[3], 4.f * m[2]);
                    word = fmaf(word, 16.f, nib);
                }
                dw[nf] |= ((unsigned int)word) << sh;
            }
        } else if (offDiag) {
            if ((t >> 7) == (rg & 3)) {
                const int st = rg >> 2;
                const int rl = (t >> 4) & 7;
                const char* base = maskLds + slot * 8192 + rl * 1024;
                float word = 0.f;
#pragma unroll
                for (int u = 3; u >= 0; --u) {
                    const int pos = ((t & 15) * 4 + u) ^ rl;
                    const f4 m = *(const f4*)(base + pos * 16);
                    float nib = fmaf(2.f, m[1], m[0]) + fmaf(8.f, m[3], 4.f * m[2]);
                    word = fmaf(word, 16.f, nib);
                }
                mw[st] |= ((unsigned int)word) << sh;
            }
        }
    };

    // prologue: slabs for iter 0 in flight (5)
#pragma unroll
    for (int s = 0; s < SLB(1); ++s) issue_slab(s);

#pragma unroll
    for (int kt = 0; kt < 24; ++kt) {
        // previous iter's LDS readers (fragments + pack) done before DMA overwrites
        asm volatile("s_waitcnt lgkmcnt(0)\n\ts_barrier" ::: "memory");

        // ---- fn staging for THIS iter (drained at this iter's wait) ----
        issue_fn(kt * 32);

        // ---- mask prefetch for iter kt+1 ----
#pragma unroll
        for (int gl = 0; gl < 6; ++gl) {
            const int s = SLB(kt + 1) + gl;
            if (s < SLB(kt + 2)) issue_slab(s);
        }

        // drain m(kt)+fn(kt); keep m(kt+1) in flight across the barrier
        if (kt == 23)           asm volatile("s_waitcnt vmcnt(0)\n\ts_barrier" ::: "memory");
        else if ((kt % 3) == 1) asm volatile("s_waitcnt vmcnt(6)\n\ts_barrier" ::: "memory");
        else                    asm volatile("s_waitcnt vmcnt(5)\n\ts_barrier" ::: "memory");

        // ---- MFMA compute ----
        short8 if_[8];
#pragma unroll
        for (int nf = 0; nf < 8; ++nf) {
            const int rr = wn * 128 + nf * 16 + cl;
            if_[nf] = *(const short8*)(IsB + rr * 64 + rdSw);
        }
#pragma unroll
        for (int mf = 0; mf < 4; ++mf) {
            const int rr = wm * 64 + mf * 16 + cl;
            const short8 jf = *(const short8*)(JsB + rr * 64 + rdSw);
#pragma unroll
            for (int nf = 0; nf < 8; ++nf)
                acc[mf][nf] = __builtin_amdgcn_mfma_f32_16x16x32_bf16(
                    jf, if_[nf], acc[mf][nf], 0, 0, 0);
        }

        // ---- pack this iter's slabs (drained at this iter's wait) ----
#pragma unroll
        for (int gl = 0; gl < 6; ++gl) {
            const int s = SLB(kt) + gl;
            if (s < SLB(kt + 1)) pack_slab(s);
        }
    }

    // ---- direct epilogue (rows i, mask[i][j]) -- masks from dw bits ----
    const int jb0 = colBase + wm * 64 + q * 4;
#pragma unroll
    for (int nf = 0; nf < 8; ++nf) {
        const int grow = rowBase + wn * 128 + nf * 16 + cl;
        const unsigned int w = dw[nf];
        float aN = 0.f, aS = 0.f, aP = 0.f;
#pragma unroll
        for (int mf = 0; mf < 4; ++mf) {
            const int jbase = jb0 + mf * 16;
#pragma unroll
            for (int reg = 0; reg < 4; ++reg) {
                const int b = mf * 4 + reg;
                float pmv = ((w >> b) & 1u) ? 1.0f : 0.0f;
                float nmv = ((w >> (16 + b)) & 1u) ? 1.0f : 0.0f;
                if (grow == jbase + reg) { pmv = 0.f; nmv = 0.f; }  // diagonal
                float v = acc[mf][nf][reg];
                float e = __builtin_amdgcn_exp2f(v * 14.4269504089f); // e^(10v)
                aN = fmaf(nmv, e, aN);
                aS = fmaf(pmv, v, aS);       // raw acc units; x10 in final_k
                aP += pmv;
            }
        }
        aN += __shfl_xor(aN, 16, 64);  aN += __shfl_xor(aN, 32, 64);
        aS += __shfl_xor(aS, 16, 64);  aS += __shfl_xor(aS, 32, 64);
        aP += __shfl_xor(aP, 16, 64);  aP += __shfl_xor(aP, 32, 64);
        if (q == 0) {
            atomicAdd(&negG[grow], aN);
            atomicAdd(&sG[grow],   aS);
            atomicAdd(&pG[grow],   aP);
        }
    }

    // ---- mirror epilogue (rows j, mask[j][i]) -- off-diagonal blocks only --
    if (offDiag) {
        const int jl2 = t >> 4;              // 0..31: strip-local j row
        const int iseg = (t & 15) * 16;      // 16-float i segment (0..255)
#pragma unroll
        for (int st = 0; st < 8; ++st) {
            __syncthreads();                 // strip buffer free
            if (wm == (st >> 1)) {           // wave-quarter owning this strip
#pragma unroll
                for (int m2 = 0; m2 < 2; ++m2) {
                    const int mf = (st & 1) * 2 + m2;
#pragma unroll
                    for (int nf = 0; nf < 8; ++nf) {
                        const int i = wn * 128 + nf * 16 + cl;
#pragma unroll
                        for (int reg = 0; reg < 4; ++reg) {
                            const int jl = m2 * 16 + q * 4 + reg;
                            T[jl * TSTRIDE2 + i] = acc[mf][nf][reg];
                        }
                    }
                }
            }
            __syncthreads();
            const int jg = colBase + st * 32 + jl2;
            const unsigned int w = mw[st];
            const f4* tv = (const f4*)(T + jl2 * TSTRIDE2 + iseg);
            float aN = 0.f, aS = 0.f, aP = 0.f;
#pragma unroll
            for (int u = 0; u < 4; ++u) {
                f4 v4 = tv[u];
#pragma unroll
                for (int e = 0; e < 4; ++e) {
                    const int b = u * 4 + e;
                    float v = v4[e];
                    float pmv = ((w >> b) & 1u) ? 1.0f : 0.0f;
                    float nmv = ((w >> (16 + b)) & 1u) ? 1.0f : 0.0f;
                    float ex = __builtin_amdgcn_exp2f(v * 14.4269504089f);
                    aN = fmaf(nmv, ex, aN);
                    aS = fmaf(pmv, v, aS);
                    aP += pmv;
                }
            }
            aN += __shfl_xor(aN, 1, 64); aN += __shfl_xor(aN, 2, 64);
            aN += __shfl_xor(aN, 4, 64); aN += __shfl_xor(aN, 8, 64);
            aS += __shfl_xor(aS, 1, 64); aS += __shfl_xor(aS, 2, 64);
            aS += __shfl_xor(aS, 4, 64); aS += __shfl_xor(aS, 8, 64);
            aP += __shfl_xor(aP, 1, 64); aP += __shfl_xor(aP, 2, 64);
            aP += __shfl_xor(aP, 4, 64); aP += __shfl_xor(aP, 8, 64);
            if ((t & 15) == 0) {
                atomicAdd(&negG[jg], aN);
                atomicAdd(&sG[jg],   aS);
                atomicAdd(&pG[jg],   aP);
            }
        }
    }
}

// ---------------------------------------------------------------------------
// Kernel 3: per-row loss assembly + mean
// loss_i = (P*log(neg) - 10*S_raw)/P (P>0 else 0);  out = mean
// ---------------------------------------------------------------------------
__global__ __launch_bounds__(1024) void final_k(const float* __restrict__ negG,
        const float* __restrict__ sG, const float* __restrict__ pG,
        float* __restrict__ out) {
    const int t = threadIdx.x;
    float sum = 0.f;
    for (int i = t; i < NROWS; i += 1024) {
        float P = pG[i];
        if (P > 0.f) {
            sum += (P * logf(negG[i]) - 10.0f * sG[i]) / P;
        }
    }
#pragma unroll
    for (int m = 32; m; m >>= 1) sum += __shfl_xor(sum, m, 64);
    __shared__ float wsum[16];
    if ((t & 63) == 0) wsum[t >> 6] = sum;
    __syncthreads();
    if (t < 16) {
        float v = wsum[t];
#pragma unroll
        for (int m = 8; m; m >>= 1) v += __shfl_xor(v, m, 16);
        if (t == 0) out[0] = v / (float)NROWS;
    }
}

// ---------------------------------------------------------------------------
extern "C" void kernel_launch(void* const* d_in, const int* in_sizes, int n_in,
                              void* d_out, int out_size, void* d_ws, size_t ws_size,
                              hipStream_t stream) {
    const float* feat  = (const float*)d_in[0];
    const float* pmask = (const float*)d_in[1];
    const float* nmask = (const float*)d_in[2];
    float* out = (float*)d_out;

    char* ws = (char*)d_ws;
    __hip_bfloat16* fn = (__hip_bfloat16*)ws;                    // 12,582,912 B
    float* negG = (float*)(ws + 12582912);
    float* sG = negG + NROWS;
    float* pG = sG + NROWS;

    // zero all three row accumulators (ws is re-poisoned before every launch)
    hipMemsetAsync(negG, 0, 3 * NROWS * sizeof(float), stream);

    normalize_k<<<NROWS, 256, 0, stream>>>(feat, fn);

    ntxent_main<<<528, 512, 0, stream>>>(fn, pmask, nmask, negG, sG, pG);

    final_k<<<1, 1024, 0, stream>>>(negG, sG, pG, out);
}

// Round 10
// 647.534 us; speedup vs baseline: 1.1321x; 1.1321x over previous
//
#include <hip/hip_runtime.h>
#include <hip/hip_bf16.h>

#define NROWS 8192
#define DDIM 768

typedef short short8 __attribute__((ext_vector_type(8)));   // 8 x bf16 (4 VGPRs)
typedef float floatx4 __attribute__((ext_vector_type(4)));  // MFMA C/D
typedef float f4 __attribute__((ext_vector_type(4)));
#define TSTRIDE2 260  // mirror transpose LDS row stride (floats)

// slab schedule: 128 slabs over 24 iters, compile-time
#define SLB(k) (((k) * 128) / 24)

// ---------------------------------------------------------------------------
// Kernel 1: row-normalize features (fp32 in) -> bf16 normalized rows
// ---------------------------------------------------------------------------
__global__ __launch_bounds__(256) void normalize_k(const float* __restrict__ f,
                                                   __hip_bfloat16* __restrict__ fn) {
    const int row = blockIdx.x;
    const int t = threadIdx.x;
    const float* fr = f + (size_t)row * DDIM;
    float v0 = fr[t];
    float v1 = fr[t + 256];
    float v2 = fr[t + 512];
    float ss = v0 * v0 + v1 * v1 + v2 * v2;
#pragma unroll
    for (int m = 32; m; m >>= 1) ss += __shfl_xor(ss, m, 64);
    __shared__ float wsum[4];
    if ((t & 63) == 0) wsum[t >> 6] = ss;
    __syncthreads();
    float tot = wsum[0] + wsum[1] + wsum[2] + wsum[3];
    float inv = 1.0f / fmaxf(sqrtf(tot), 1e-8f);
    __hip_bfloat16* o = fn + (size_t)row * DDIM;
    o[t]       = __float2bfloat16(v0 * inv);
    o[t + 256] = __float2bfloat16(v1 * inv);
    o[t + 512] = __float2bfloat16(v2 * inv);
}

// ---------------------------------------------------------------------------
// Kernel 2: SYMMETRIC bf16 GEMM (s = 10 * fn fn^T) + fused mask reductions.
// R18 = R17 (256x256 tile, absmax-0-verified) with the spill removed:
//  - R17's WRITE_SIZE 172 MB = ~6-10 VGPRs respilled per iter under the
//    128-arch-VGPR cap (acc[4][8]=128 AGPRs uses the other half of the
//    256-reg unified budget at 8 waves/CU). Fix: process nf in TWO HALVES
//    of 4 (if_[4], jf re-read per half) -> frees 16 arch VGPRs.
//  - pack moved into the DMA shadow (issue->pack->wait), R15's proven
//    placement. Legal: pack(kt) reads m(kt), drained at wait(kt-1); its
//    ds_reads complete before slot reuse via next iter's top lgkmcnt(0).
// Bytes rationale (R8/R15/R16: wall ~= vmem bytes / ~6.9 TB/s fabric):
// fn 818->415 MB at 256^2; masks 537 MB fixed; spill 0 -> ~0.95 GB total.
// vmcnt ladder (simulated, matches R17-passed): prologue m(0){5}; per iter
// issue fn{4}+m(kt+1){c}; wait vmcnt(SLB(kt+2)-SLB(kt+1)) = 6 iff kt%3==1
// else 5; kt=23 -> 0. Slab slot s%12 (reuse distance >2 iters).
// ---------------------------------------------------------------------------
__global__ __launch_bounds__(512, 2) void ntxent_main(
        const __hip_bfloat16* __restrict__ fn,
        const float* __restrict__ pmask, const float* __restrict__ nmask,
        float* __restrict__ negG, float* __restrict__ sG,
        float* __restrict__ pG) {
    __shared__ __align__(16) char smem[131072];  // fn 32K | 12 mask slots 96K
    char* IsB = smem;                            // 256 rows x 64B
    char* JsB = smem + 16384;
    char* maskLds = smem + 32768;                // 12 x 8192
    float* T = (float*)smem;                     // mirror transpose alias (epilogue)

    const int t = threadIdx.x;
    const int lane = t & 63;
    const int wv = t >> 6;          // 0..7
    const int wn = wv & 1;          // i-half (128 rows)
    const int wm = wv >> 1;         // j-quarter (64 cols)
    const int q  = lane >> 4;
    const int cl = lane & 15;

    // XCD-chunked swizzle (528 = 8*66, bijective)
    const int bt0 = blockIdx.x;
    const int bt = (bt0 & 7) * 66 + (bt0 >> 3);

    // triangular decode: block bt -> (c, r) with c <= r   (32 tiles)
    int r = (int)((sqrtf(8.0f * (float)bt + 1.0f) - 1.0f) * 0.5f);
    while ((r + 1) * (r + 2) / 2 <= bt) ++r;
    while (r * (r + 1) / 2 > bt) --r;
    const int c = bt - r * (r + 1) / 2;
    const int rowBase = c * 256;     // i-tile
    const int colBase = r * 256;     // j-tile
    const bool offDiag = (c != r);

    const int rdSw = ((q ^ ((cl >> 1) & 3)) << 4);

    // slab DMA per-thread constants: row in slab (8), source-swizzled quad (64)
    const int sRow = t >> 6;                        // 0..7
    const int sChunk = (t & 63) ^ (sRow & 7);       // source quad (pre-swizzled)

    floatx4 acc[4][8];            // [mf (j)][nf (i)] -- 128 AGPRs
#pragma unroll
    for (int mf = 0; mf < 4; ++mf)
#pragma unroll
        for (int nf = 0; nf < 8; ++nf)
            acc[mf][nf] = (floatx4){0.f, 0.f, 0.f, 0.f};

    // packed mask words: direct per nf, mirror per st; bits [15:0]=pos [31:16]=neg
    unsigned int dw[8] = {0u,0u,0u,0u,0u,0u,0u,0u};
    unsigned int mw[8] = {0u,0u,0u,0u,0u,0u,0u,0u};

    // slab s in [0,128): side=s>>6 (0 direct,1 mirror), h=s&63, rg=h>>1, isN=h&1
    auto issue_slab = [&](int s) {
        const int slot = s % 12;
        const int side = s >> 6;
        const int rg   = (s & 63) >> 1;
        const float* mp = (s & 1) ? nmask : pmask;
        const int rowG = (side ? colBase : rowBase) + rg * 8 + sRow;
        const int colG = (side ? rowBase : colBase) + sChunk * 4;
        const float* src = mp + (size_t)rowG * NROWS + colG;
        __builtin_amdgcn_global_load_lds(
            (const __attribute__((address_space(1))) void*)src,
            (__attribute__((address_space(3))) void*)(maskLds + slot * 8192 + t * 16),
            16, 0, 0);
    };

    // fn staging for K-step k0 (single buffer): 4 x global_load_lds
    auto issue_fn = [&](int k0) {
#pragma unroll
        for (int it = 0; it < 2; ++it) {
            const int s = it * 512 + t;              // 16B slot 0..1023
            const int rr = s >> 2;                   // 0..255
            const int cg = (s & 3) ^ ((rr >> 1) & 3);
            const __hip_bfloat16* ga = fn + (size_t)(rowBase + rr) * DDIM + k0 + cg * 8;
            const __hip_bfloat16* gb = fn + (size_t)(colBase + rr) * DDIM + k0 + cg * 8;
            __builtin_amdgcn_global_load_lds(
                (const __attribute__((address_space(1))) void*)ga,
                (__attribute__((address_space(3))) void*)(IsB + s * 16), 16, 0, 0);
            __builtin_amdgcn_global_load_lds(
                (const __attribute__((address_space(1))) void*)gb,
                (__attribute__((address_space(3))) void*)(JsB + s * 16), 16, 0, 0);
        }
    };

    // pack: nibble = m0+2m1+4m2+8m3 (exact 0/1); word = sum 16^mf * nib
    auto pack_slab = [&](int s) {
        const int slot = s % 12;
        const int side = s >> 6;
        const int rg   = (s & 63) >> 1;
        const int sh   = (s & 1) ? 16 : 0;
        if (side == 0) {
            if (wn == ((rg >> 4) & 1) && (cl >> 3) == (rg & 1)) {
                const int nf = (rg >> 1) & 7;
                const int rl = cl & 7;
                const char* base = maskLds + slot * 8192 + rl * 1024;
                float word = 0.f;
#pragma unroll
                for (int mf = 3; mf >= 0; --mf) {
                    const int pos = (wm * 16 + mf * 4 + q) ^ rl;
                    const f4 m = *(const f4*)(base + pos * 16);
                    float nib = fmaf(2.f, m[1], m[0]) + fmaf(8.f, m[3], 4.f * m[2]);
                    word = fmaf(word, 16.f, nib);
                }
                dw[nf] |= ((unsigned int)word) << sh;
            }
        } else if (offDiag) {
            if ((t >> 7) == (rg & 3)) {
                const int st = rg >> 2;
                const int rl = (t >> 4) & 7;
                const char* base = maskLds + slot * 8192 + rl * 1024;
                float word = 0.f;
#pragma unroll
                for (int u = 3; u >= 0; --u) {
                    const int pos = ((t & 15) * 4 + u) ^ rl;
                    const f4 m = *(const f4*)(base + pos * 16);
                    float nib = fmaf(2.f, m[1], m[0]) + fmaf(8.f, m[3], 4.f * m[2]);
                    word = fmaf(word, 16.f, nib);
                }
                mw[st] |= ((unsigned int)word) << sh;
            }
        }
    };

    // prologue: slabs for iter 0 in flight (5)
#pragma unroll
    for (int s = 0; s < SLB(1); ++s) issue_slab(s);

#pragma unroll
    for (int kt = 0; kt < 24; ++kt) {
        // previous iter's LDS readers (fragments + pack) done before DMA overwrites
        asm volatile("s_waitcnt lgkmcnt(0)\n\ts_barrier" ::: "memory");

        // ---- fn staging for THIS iter (drained at this iter's wait) ----
        issue_fn(kt * 32);

        // ---- mask prefetch for iter kt+1 ----
#pragma unroll
        for (int gl = 0; gl < 6; ++gl) {
            const int s = SLB(kt + 1) + gl;
            if (s < SLB(kt + 2)) issue_slab(s);
        }

        // ---- pack this iter's slabs IN THE DMA SHADOW (drained at wait(kt-1)) --
#pragma unroll
        for (int gl = 0; gl < 6; ++gl) {
            const int s = SLB(kt) + gl;
            if (s < SLB(kt + 1)) pack_slab(s);
        }

        // drain m(kt)+fn(kt); keep m(kt+1) in flight across the barrier
        if (kt == 23)           asm volatile("s_waitcnt vmcnt(0)\n\ts_barrier" ::: "memory");
        else if ((kt % 3) == 1) asm volatile("s_waitcnt vmcnt(6)\n\ts_barrier" ::: "memory");
        else                    asm volatile("s_waitcnt vmcnt(5)\n\ts_barrier" ::: "memory");

        // ---- MFMA compute: two nf-halves of 4 (16 fewer live VGPRs) ----
#pragma unroll
        for (int h = 0; h < 2; ++h) {
            short8 if_[4];
#pragma unroll
            for (int nf = 0; nf < 4; ++nf) {
                const int rr = wn * 128 + (h * 4 + nf) * 16 + cl;
                if_[nf] = *(const short8*)(IsB + rr * 64 + rdSw);
            }
#pragma unroll
            for (int mf = 0; mf < 4; ++mf) {
                const int rr = wm * 64 + mf * 16 + cl;
                const short8 jf = *(const short8*)(JsB + rr * 64 + rdSw);
#pragma unroll
                for (int nf = 0; nf < 4; ++nf)
                    acc[mf][h * 4 + nf] = __builtin_amdgcn_mfma_f32_16x16x32_bf16(
                        jf, if_[nf], acc[mf][h * 4 + nf], 0, 0, 0);
            }
        }
    }

    // ---- direct epilogue (rows i, mask[i][j]) -- masks from dw bits ----
    const int jb0 = colBase + wm * 64 + q * 4;
#pragma unroll
    for (int nf = 0; nf < 8; ++nf) {
        const int grow = rowBase + wn * 128 + nf * 16 + cl;
        const unsigned int w = dw[nf];
        float aN = 0.f, aS = 0.f, aP = 0.f;
#pragma unroll
        for (int mf = 0; mf < 4; ++mf) {
            const int jbase = jb0 + mf * 16;
#pragma unroll
            for (int reg = 0; reg < 4; ++reg) {
                const int b = mf * 4 + reg;
                float pmv = ((w >> b) & 1u) ? 1.0f : 0.0f;
                float nmv = ((w >> (16 + b)) & 1u) ? 1.0f : 0.0f;
                if (grow == jbase + reg) { pmv = 0.f; nmv = 0.f; }  // diagonal
                float v = acc[mf][nf][reg];
                float e = __builtin_amdgcn_exp2f(v * 14.4269504089f); // e^(10v)
                aN = fmaf(nmv, e, aN);
                aS = fmaf(pmv, v, aS);       // raw acc units; x10 in final_k
                aP += pmv;
            }
        }
        aN += __shfl_xor(aN, 16, 64);  aN += __shfl_xor(aN, 32, 64);
        aS += __shfl_xor(aS, 16, 64);  aS += __shfl_xor(aS, 32, 64);
        aP += __shfl_xor(aP, 16, 64);  aP += __shfl_xor(aP, 32, 64);
        if (q == 0) {
            atomicAdd(&negG[grow], aN);
            atomicAdd(&sG[grow],   aS);
            atomicAdd(&pG[grow],   aP);
        }
    }

    // ---- mirror epilogue (rows j, mask[j][i]) -- off-diagonal blocks only --
    if (offDiag) {
        const int jl2 = t >> 4;              // 0..31: strip-local j row
        const int iseg = (t & 15) * 16;      // 16-float i segment (0..255)
#pragma unroll
        for (int st = 0; st < 8; ++st) {
            __syncthreads();                 // strip buffer free
            if (wm == (st >> 1)) {           // wave-quarter owning this strip
#pragma unroll
                for (int m2 = 0; m2 < 2; ++m2) {
                    const int mf = (st & 1) * 2 + m2;
#pragma unroll
                    for (int nf = 0; nf < 8; ++nf) {
                        const int i = wn * 128 + nf * 16 + cl;
#pragma unroll
                        for (int reg = 0; reg < 4; ++reg) {
                            const int jl = m2 * 16 + q * 4 + reg;
                            T[jl * TSTRIDE2 + i] = acc[mf][nf][reg];
                        }
                    }
                }
            }
            __syncthreads();
            const int jg = colBase + st * 32 + jl2;
            const unsigned int w = mw[st];
            const f4* tv = (const f4*)(T + jl2 * TSTRIDE2 + iseg);
            float aN = 0.f, aS = 0.f, aP = 0.f;
#pragma unroll
            for (int u = 0; u < 4; ++u) {
                f4 v4 = tv[u];
#pragma unroll
                for (int e = 0; e < 4; ++e) {
                    const int b = u * 4 + e;
                    float v = v4[e];
                    float pmv = ((w >> b) & 1u) ? 1.0f : 0.0f;
                    float nmv = ((w >> (16 + b)) & 1u) ? 1.0f : 0.0f;
                    float ex = __builtin_amdgcn_exp2f(v * 14.4269504089f);
                    aN = fmaf(nmv, ex, aN);
                    aS = fmaf(pmv, v, aS);
                    aP += pmv;
                }
            }
            aN += __shfl_xor(aN, 1, 64); aN += __shfl_xor(aN, 2, 64);
            aN += __shfl_xor(aN, 4, 64); aN += __shfl_xor(aN, 8, 64);
            aS += __shfl_xor(aS, 1, 64); aS += __shfl_xor(aS, 2, 64);
            aS += __shfl_xor(aS, 4, 64); aS += __shfl_xor(aS, 8, 64);
            aP += __shfl_xor(aP, 1, 64); aP += __shfl_xor(aP, 2, 64);
            aP += __shfl_xor(aP, 4, 64); aP += __shfl_xor(aP, 8, 64);
            if ((t & 15) == 0) {
                atomicAdd(&negG[jg], aN);
                atomicAdd(&sG[jg],   aS);
                atomicAdd(&pG[jg],   aP);
            }
        }
    }
}

// ---------------------------------------------------------------------------
// Kernel 3: per-row loss assembly + mean
// loss_i = (P*log(neg) - 10*S_raw)/P (P>0 else 0);  out = mean
// ---------------------------------------------------------------------------
__global__ __launch_bounds__(1024) void final_k(const float* __restrict__ negG,
        const float* __restrict__ sG, const float* __restrict__ pG,
        float* __restrict__ out) {
    const int t = threadIdx.x;
    float sum = 0.f;
    for (int i = t; i < NROWS; i += 1024) {
        float P = pG[i];
        if (P > 0.f) {
            sum += (P * logf(negG[i]) - 10.0f * sG[i]) / P;
        }
    }
#pragma unroll
    for (int m = 32; m; m >>= 1) sum += __shfl_xor(sum, m, 64);
    __shared__ float wsum[16];
    if ((t & 63) == 0) wsum[t >> 6] = sum;
    __syncthreads();
    if (t < 16) {
        float v = wsum[t];
#pragma unroll
        for (int m = 8; m; m >>= 1) v += __shfl_xor(v, m, 16);
        if (t == 0) out[0] = v / (float)NROWS;
    }
}

// ---------------------------------------------------------------------------
extern "C" void kernel_launch(void* const* d_in, const int* in_sizes, int n_in,
                              void* d_out, int out_size, void* d_ws, size_t ws_size,
                              hipStream_t stream) {
    const float* feat  = (const float*)d_in[0];
    const float* pmask = (const float*)d_in[1];
    const float* nmask = (const float*)d_in[2];
    float* out = (float*)d_out;

    char* ws = (char*)d_ws;
    __hip_bfloat16* fn = (__hip_bfloat16*)ws;                    // 12,582,912 B
    float* negG = (float*)(ws + 12582912);
    float* sG = negG + NROWS;
    float* pG = sG + NROWS;

    // zero all three row accumulators (ws is re-poisoned before every launch)
    hipMemsetAsync(negG, 0, 3 * NROWS * sizeof(float), stream);

    normalize_k<<<NROWS, 256, 0, stream>>>(feat, fn);

    ntxent_main<<<528, 512, 0, stream>>>(fn, pmask, nmask, negG, sG, pG);

    final_k<<<1, 1024, 0, stream>>>(negG, sG, pG, out);
}

// Round 11
// 615.994 us; speedup vs baseline: 1.1901x; 1.0512x over previous
//
#include <hip/hip_runtime.h>
#include <hip/hip_bf16.h>

#define NROWS 8192
#define DDIM 768

typedef short short8 __attribute__((ext_vector_type(8)));   // 8 x bf16 (4 VGPRs)
typedef float floatx4 __attribute__((ext_vector_type(4)));  // MFMA C/D
typedef float f4 __attribute__((ext_vector_type(4)));
#define TSTRIDE2 260  // mirror transpose LDS row stride (floats)

// slab schedule: 128 slabs over 24 iters, compile-time
#define SLB(k) (((k) * 128) / 24)

// ---------------------------------------------------------------------------
// Kernel 1: row-normalize features (fp32 in) -> bf16 normalized rows
// ---------------------------------------------------------------------------
__global__ __launch_bounds__(256) void normalize_k(const float* __restrict__ f,
                                                   __hip_bfloat16* __restrict__ fn) {
    const int row = blockIdx.x;
    const int t = threadIdx.x;
    const float* fr = f + (size_t)row * DDIM;
    float v0 = fr[t];
    float v1 = fr[t + 256];
    float v2 = fr[t + 512];
    float ss = v0 * v0 + v1 * v1 + v2 * v2;
#pragma unroll
    for (int m = 32; m; m >>= 1) ss += __shfl_xor(ss, m, 64);
    __shared__ float wsum[4];
    if ((t & 63) == 0) wsum[t >> 6] = ss;
    __syncthreads();
    float tot = wsum[0] + wsum[1] + wsum[2] + wsum[3];
    float inv = 1.0f / fmaxf(sqrtf(tot), 1e-8f);
    __hip_bfloat16* o = fn + (size_t)row * DDIM;
    o[t]       = __float2bfloat16(v0 * inv);
    o[t + 256] = __float2bfloat16(v1 * inv);
    o[t + 512] = __float2bfloat16(v2 * inv);
}

// ---------------------------------------------------------------------------
// Kernel 2: SYMMETRIC bf16 GEMM (s = 10 * fn fn^T) + fused mask reductions.
// R19: 256x256 tile with a formally-correct fully-hidden pipeline.
// R18 post-mortem: (a) residual spill (WRITE 41 MB) -- 512-thr blocks cap
// the unified budget at 256/wave; acc=128 AGPR leaves 128 VGPR and R18
// needed ~132; (b) R18's pack-in-shadow was a formal race (m(kt) only
// drained at wait(kt), AFTER pack(kt)); passed on timing luck only.
// New iteration (in-order queue simulated):
//   top lgkmcnt(0)+barrier; issue fn(kt+1)->buf^1; wait vmcnt(4)+barrier
//   [drains fn(kt)+m(kt); queue fn(kt),m(kt),fn(kt+1) -> keep newest 4;
//    kt=23 -> vmcnt(0)]; pack m(kt) [legal: drained]; barrier; issue
//   m(kt+1) [~1 iter flight to wait(kt+1)]; MFMA from buf[kt&1].
// fn dbuf 2x32K + 8 mask slots x 8K = 128 KB LDS (1 block/CU). Slot s%8
// safe: prior occupant is m(kt-1)/m(kt), both packed before issue.
// Register fix: 4-quarter fragments (if_[2] + 1 jf live) frees ~8-12 VGPRs
// -> fits the 128-VGPR side; spill sentinel = WRITE_SIZE ~9.3 MB.
// Epilogues / pack math / bit layout: byte-identical to R17/R18 (verified).
// ---------------------------------------------------------------------------
__global__ __launch_bounds__(512, 2) void ntxent_main(
        const __hip_bfloat16* __restrict__ fn,
        const float* __restrict__ pmask, const float* __restrict__ nmask,
        float* __restrict__ negG, float* __restrict__ sG,
        float* __restrict__ pG) {
    __shared__ __align__(16) char smem[131072];  // fn dbuf 64K | 8 mask slots 64K
    char* fnBuf0 = smem;                         // [Is 16K | Js 16K]
    char* fnBuf1 = smem + 32768;
    char* maskLds = smem + 65536;                // 8 x 8192
    float* T = (float*)smem;                     // mirror transpose alias (epilogue)

    const int t = threadIdx.x;
    const int lane = t & 63;
    const int wv = t >> 6;          // 0..7
    const int wn = wv & 1;          // i-half (128 rows)
    const int wm = wv >> 1;         // j-quarter (64 cols)
    const int q  = lane >> 4;
    const int cl = lane & 15;

    // XCD-chunked swizzle (528 = 8*66, bijective)
    const int bt0 = blockIdx.x;
    const int bt = (bt0 & 7) * 66 + (bt0 >> 3);

    // triangular decode: block bt -> (c, r) with c <= r   (32 tiles)
    int r = (int)((sqrtf(8.0f * (float)bt + 1.0f) - 1.0f) * 0.5f);
    while ((r + 1) * (r + 2) / 2 <= bt) ++r;
    while (r * (r + 1) / 2 > bt) --r;
    const int c = bt - r * (r + 1) / 2;
    const int rowBase = c * 256;     // i-tile
    const int colBase = r * 256;     // j-tile
    const bool offDiag = (c != r);

    const int rdSw = ((q ^ ((cl >> 1) & 3)) << 4);

    // slab DMA per-thread constants: row in slab (8), source-swizzled quad (64)
    const int sRow = t >> 6;                        // 0..7
    const int sChunk = (t & 63) ^ (sRow & 7);       // source quad (pre-swizzled)

    floatx4 acc[4][8];            // [mf (j)][nf (i)] -- 128 AGPRs
#pragma unroll
    for (int mf = 0; mf < 4; ++mf)
#pragma unroll
        for (int nf = 0; nf < 8; ++nf)
            acc[mf][nf] = (floatx4){0.f, 0.f, 0.f, 0.f};

    // packed mask words: direct per nf, mirror per st; bits [15:0]=pos [31:16]=neg
    unsigned int dw[8] = {0u,0u,0u,0u,0u,0u,0u,0u};
    unsigned int mw[8] = {0u,0u,0u,0u,0u,0u,0u,0u};

    // slab s in [0,128): side=s>>6 (0 direct,1 mirror), h=s&63, rg=h>>1, isN=h&1
    auto issue_slab = [&](int s) {
        const int slot = s & 7;
        const int side = s >> 6;
        const int rg   = (s & 63) >> 1;
        const float* mp = (s & 1) ? nmask : pmask;
        const int rowG = (side ? colBase : rowBase) + rg * 8 + sRow;
        const int colG = (side ? rowBase : colBase) + sChunk * 4;
        const float* src = mp + (size_t)rowG * NROWS + colG;
        __builtin_amdgcn_global_load_lds(
            (const __attribute__((address_space(1))) void*)src,
            (__attribute__((address_space(3))) void*)(maskLds + slot * 8192 + t * 16),
            16, 0, 0);
    };

    // fn staging into buffer for K-step k0: 4 x global_load_lds
    auto issue_fn = [&](char* buf, int k0) {
#pragma unroll
        for (int it = 0; it < 2; ++it) {
            const int s = it * 512 + t;              // 16B slot 0..1023
            const int rr = s >> 2;                   // 0..255
            const int cg = (s & 3) ^ ((rr >> 1) & 3);
            const __hip_bfloat16* ga = fn + (size_t)(rowBase + rr) * DDIM + k0 + cg * 8;
            const __hip_bfloat16* gb = fn + (size_t)(colBase + rr) * DDIM + k0 + cg * 8;
            __builtin_amdgcn_global_load_lds(
                (const __attribute__((address_space(1))) void*)ga,
                (__attribute__((address_space(3))) void*)(buf + s * 16), 16, 0, 0);
            __builtin_amdgcn_global_load_lds(
                (const __attribute__((address_space(1))) void*)gb,
                (__attribute__((address_space(3))) void*)(buf + 16384 + s * 16), 16, 0, 0);
        }
    };

    // pack: nibble = m0+2m1+4m2+8m3 (exact 0/1); word = sum 16^mf * nib
    auto pack_slab = [&](int s) {
        const int slot = s & 7;
        const int side = s >> 6;
        const int rg   = (s & 63) >> 1;
        const int sh   = (s & 1) ? 16 : 0;
        if (side == 0) {
            if (wn == ((rg >> 4) & 1) && (cl >> 3) == (rg & 1)) {
                const int nf = (rg >> 1) & 7;
                const int rl = cl & 7;
                const char* base = maskLds + slot * 8192 + rl * 1024;
                float word = 0.f;
#pragma unroll
                for (int mf = 3; mf >= 0; --mf) {
                    const int pos = (wm * 16 + mf * 4 + q) ^ rl;
                    const f4 m = *(const f4*)(base + pos * 16);
                    float nib = fmaf(2.f, m[1], m[0]) + fmaf(8.f, m[3], 4.f * m[2]);
                    word = fmaf(word, 16.f, nib);
                }
                dw[nf] |= ((unsigned int)word) << sh;
            }
        } else if (offDiag) {
            if ((t >> 7) == (rg & 3)) {
                const int st = rg >> 2;
                const int rl = (t >> 4) & 7;
                const char* base = maskLds + slot * 8192 + rl * 1024;
                float word = 0.f;
#pragma unroll
                for (int u = 3; u >= 0; --u) {
                    const int pos = ((t & 15) * 4 + u) ^ rl;
                    const f4 m = *(const f4*)(base + pos * 16);
                    float nib = fmaf(2.f, m[1], m[0]) + fmaf(8.f, m[3], 4.f * m[2]);
                    word = fmaf(word, 16.f, nib);
                }
                mw[st] |= ((unsigned int)word) << sh;
            }
        }
    };

    // prologue: fn(0) + m(0) in flight, full drain once
    issue_fn(fnBuf0, 0);
#pragma unroll
    for (int s = 0; s < SLB(1); ++s) issue_slab(s);
    asm volatile("s_waitcnt vmcnt(0)" ::: "memory");

#pragma unroll
    for (int kt = 0; kt < 24; ++kt) {
        // prev MFMA fragment reads + pack reads consumed before DMA overwrites
        asm volatile("s_waitcnt lgkmcnt(0)\n\ts_barrier" ::: "memory");

        // ---- fn prefetch for iter kt+1 into the other buffer ----
        if (kt < 23) issue_fn((kt & 1) ? fnBuf0 : fnBuf1, (kt + 1) * 32);

        // drain fn(kt)+m(kt) (issued last iter); keep fn(kt+1){4}
        if (kt < 23) asm volatile("s_waitcnt vmcnt(4)\n\ts_barrier" ::: "memory");
        else         asm volatile("s_waitcnt vmcnt(0)\n\ts_barrier" ::: "memory");

        // ---- pack m(kt): formally drained by the wait above ----
#pragma unroll
        for (int gl = 0; gl < 6; ++gl) {
            const int s = SLB(kt) + gl;
            if (s < SLB(kt + 1)) pack_slab(s);
        }
        // all waves' pack reads consumed before slot overwrite
        asm volatile("s_barrier" ::: "memory");

        // ---- mask prefetch for iter kt+1 (lands by wait(kt+1)) ----
        if (kt < 23) {
#pragma unroll
            for (int gl = 0; gl < 6; ++gl) {
                const int s = SLB(kt + 1) + gl;
                if (s < SLB(kt + 2)) issue_slab(s);
            }
        }

        // ---- MFMA compute from buf[kt&1]: four nf-quarters (min live regs) ----
        const char* IsC = (kt & 1) ? fnBuf1 : fnBuf0;
        const char* JsC = IsC + 16384;
#pragma unroll
        for (int h = 0; h < 4; ++h) {
            short8 if_[2];
#pragma unroll
            for (int nf = 0; nf < 2; ++nf) {
                const int rr = wn * 128 + (h * 2 + nf) * 16 + cl;
                if_[nf] = *(const short8*)(IsC + rr * 64 + rdSw);
            }
#pragma unroll
            for (int mf = 0; mf < 4; ++mf) {
                const int rr = wm * 64 + mf * 16 + cl;
                const short8 jf = *(const short8*)(JsC + rr * 64 + rdSw);
#pragma unroll
                for (int nf = 0; nf < 2; ++nf)
                    acc[mf][h * 2 + nf] = __builtin_amdgcn_mfma_f32_16x16x32_bf16(
                        jf, if_[nf], acc[mf][h * 2 + nf], 0, 0, 0);
            }
        }
    }

    // ---- direct epilogue (rows i, mask[i][j]) -- masks from dw bits ----
    const int jb0 = colBase + wm * 64 + q * 4;
#pragma unroll
    for (int nf = 0; nf < 8; ++nf) {
        const int grow = rowBase + wn * 128 + nf * 16 + cl;
        const unsigned int w = dw[nf];
        float aN = 0.f, aS = 0.f, aP = 0.f;
#pragma unroll
        for (int mf = 0; mf < 4; ++mf) {
            const int jbase = jb0 + mf * 16;
#pragma unroll
            for (int reg = 0; reg < 4; ++reg) {
                const int b = mf * 4 + reg;
                float pmv = ((w >> b) & 1u) ? 1.0f : 0.0f;
                float nmv = ((w >> (16 + b)) & 1u) ? 1.0f : 0.0f;
                if (grow == jbase + reg) { pmv = 0.f; nmv = 0.f; }  // diagonal
                float v = acc[mf][nf][reg];
                float e = __builtin_amdgcn_exp2f(v * 14.4269504089f); // e^(10v)
                aN = fmaf(nmv, e, aN);
                aS = fmaf(pmv, v, aS);       // raw acc units; x10 in final_k
                aP += pmv;
            }
        }
        aN += __shfl_xor(aN, 16, 64);  aN += __shfl_xor(aN, 32, 64);
        aS += __shfl_xor(aS, 16, 64);  aS += __shfl_xor(aS, 32, 64);
        aP += __shfl_xor(aP, 16, 64);  aP += __shfl_xor(aP, 32, 64);
        if (q == 0) {
            atomicAdd(&negG[grow], aN);
            atomicAdd(&sG[grow],   aS);
            atomicAdd(&pG[grow],   aP);
        }
    }

    // ---- mirror epilogue (rows j, mask[j][i]) -- off-diagonal blocks only --
    if (offDiag) {
        const int jl2 = t >> 4;              // 0..31: strip-local j row
        const int iseg = (t & 15) * 16;      // 16-float i segment (0..255)
#pragma unroll
        for (int st = 0; st < 8; ++st) {
            __syncthreads();                 // strip buffer free
            if (wm == (st >> 1)) {           // wave-quarter owning this strip
#pragma unroll
                for (int m2 = 0; m2 < 2; ++m2) {
                    const int mf = (st & 1) * 2 + m2;
#pragma unroll
                    for (int nf = 0; nf < 8; ++nf) {
                        const int i = wn * 128 + nf * 16 + cl;
#pragma unroll
                        for (int reg = 0; reg < 4; ++reg) {
                            const int jl = m2 * 16 + q * 4 + reg;
                            T[jl * TSTRIDE2 + i] = acc[mf][nf][reg];
                        }
                    }
                }
            }
            __syncthreads();
            const int jg = colBase + st * 32 + jl2;
            const unsigned int w = mw[st];
            const f4* tv = (const f4*)(T + jl2 * TSTRIDE2 + iseg);
            float aN = 0.f, aS = 0.f, aP = 0.f;
#pragma unroll
            for (int u = 0; u < 4; ++u) {
                f4 v4 = tv[u];
#pragma unroll
                for (int e = 0; e < 4; ++e) {
                    const int b = u * 4 + e;
                    float v = v4[e];
                    float pmv = ((w >> b) & 1u) ? 1.0f : 0.0f;
                    float nmv = ((w >> (16 + b)) & 1u) ? 1.0f : 0.0f;
                    float ex = __builtin_amdgcn_exp2f(v * 14.4269504089f);
                    aN = fmaf(nmv, ex, aN);
                    aS = fmaf(pmv, v, aS);
                    aP += pmv;
                }
            }
            aN += __shfl_xor(aN, 1, 64); aN += __shfl_xor(aN, 2, 64);
            aN += __shfl_xor(aN, 4, 64); aN += __shfl_xor(aN, 8, 64);
            aS += __shfl_xor(aS, 1, 64); aS += __shfl_xor(aS, 2, 64);
            aS += __shfl_xor(aS, 4, 64); aS += __shfl_xor(aS, 8, 64);
            aP += __shfl_xor(aP, 1, 64); aP += __shfl_xor(aP, 2, 64);
            aP += __shfl_xor(aP, 4, 64); aP += __shfl_xor(aP, 8, 64);
            if ((t & 15) == 0) {
                atomicAdd(&negG[jg], aN);
                atomicAdd(&sG[jg],   aS);
                atomicAdd(&pG[jg],   aP);
            }
        }
    }
}

// ---------------------------------------------------------------------------
// Kernel 3: per-row loss assembly + mean
// loss_i = (P*log(neg) - 10*S_raw)/P (P>0 else 0);  out = mean
// ---------------------------------------------------------------------------
__global__ __launch_bounds__(1024) void final_k(const float* __restrict__ negG,
        const float* __restrict__ sG, const float* __restrict__ pG,
        float* __restrict__ out) {
    const int t = threadIdx.x;
    float sum = 0.f;
    for (int i = t; i < NROWS; i += 1024) {
        float P = pG[i];
        if (P > 0.f) {
            sum += (P * logf(negG[i]) - 10.0f * sG[i]) / P;
        }
    }
#pragma unroll
    for (int m = 32; m; m >>= 1) sum += __shfl_xor(sum, m, 64);
    __shared__ float wsum[16];
    if ((t & 63) == 0) wsum[t >> 6] = sum;
    __syncthreads();
    if (t < 16) {
        float v = wsum[t];
#pragma unroll
        for (int m = 8; m; m >>= 1) v += __shfl_xor(v, m, 16);
        if (t == 0) out[0] = v / (float)NROWS;
    }
}

// ---------------------------------------------------------------------------
extern "C" void kernel_launch(void* const* d_in, const int* in_sizes, int n_in,
                              void* d_out, int out_size, void* d_ws, size_t ws_size,
                              hipStream_t stream) {
    const float* feat  = (const float*)d_in[0];
    const float* pmask = (const float*)d_in[1];
    const float* nmask = (const float*)d_in[2];
    float* out = (float*)d_out;

    char* ws = (char*)d_ws;
    __hip_bfloat16* fn = (__hip_bfloat16*)ws;                    // 12,582,912 B
    float* negG = (float*)(ws + 12582912);
    float* sG = negG + NROWS;
    float* pG = sG + NROWS;

    // zero all three row accumulators (ws is re-poisoned before every launch)
    hipMemsetAsync(negG, 0, 3 * NROWS * sizeof(float), stream);

    normalize_k<<<NROWS, 256, 0, stream>>>(feat, fn);

    ntxent_main<<<528, 512, 0, stream>>>(fn, pmask, nmask, negG, sG, pG);

    final_k<<<1, 1024, 0, stream>>>(negG, sG, pG, out);
}

// Round 12
// 573.136 us; speedup vs baseline: 1.2791x; 1.0748x over previous
//
#include <hip/hip_runtime.h>
#include <hip/hip_bf16.h>

#define NROWS 8192
#define DDIM 768

typedef short short8 __attribute__((ext_vector_type(8)));   // 8 x bf16 (4 VGPRs)
typedef float floatx4 __attribute__((ext_vector_type(4)));  // MFMA C/D
typedef float f4 __attribute__((ext_vector_type(4)));
#define TSTRIDE 132   // transpose LDS row stride (floats): 2-way banks, 16B aligned

// ---------------------------------------------------------------------------
// Kernel 1: row-normalize features (fp32 in) -> bf16 normalized rows
// ---------------------------------------------------------------------------
__global__ __launch_bounds__(256) void normalize_k(const float* __restrict__ f,
                                                   __hip_bfloat16* __restrict__ fn) {
    const int row = blockIdx.x;
    const int t = threadIdx.x;
    const float* fr = f + (size_t)row * DDIM;
    float v0 = fr[t];
    float v1 = fr[t + 256];
    float v2 = fr[t + 512];
    float ss = v0 * v0 + v1 * v1 + v2 * v2;
#pragma unroll
    for (int m = 32; m; m >>= 1) ss += __shfl_xor(ss, m, 64);
    __shared__ float wsum[4];
    if ((t & 63) == 0) wsum[t >> 6] = ss;
    __syncthreads();
    float tot = wsum[0] + wsum[1] + wsum[2] + wsum[3];
    float inv = 1.0f / fmaxf(sqrtf(tot), 1e-8f);
    __hip_bfloat16* o = fn + (size_t)row * DDIM;
    o[t]       = __float2bfloat16(v0 * inv);
    o[t + 256] = __float2bfloat16(v1 * inv);
    o[t + 512] = __float2bfloat16(v2 * inv);
}

// ---------------------------------------------------------------------------
// Kernel 2: SYMMETRIC bf16 GEMM (s = 10 * fn fn^T) + fused mask reductions.
// FINAL (= R15, best harness-verified: 193 us kernel / 573.6 us total).
// Session summary of structural evidence:
//  - masks (537 MB, read-once) stream through the K-loop as 8-row slabs via
//    global_load_lds, depth-2 prefetch, counted vmcnt (never 0 mid-loop);
//    bit-packed in the DMA shadow via fma-nibble (masks are exact 0/1);
//    epilogues consume bits -> zero epilogue HBM.
//  - 128^2 tile beats 256^2 (tried 3x: 354/267/236 vs 193): 256^2's 128 KB
//    LDS -> 1 block/CU -> every vmcnt+barrier stalls the whole CU; delivery
//    rate is occupancy-dependent, and ~2.4 blocks/CU at 128^2 wins despite
//    2x fn bytes. fn dbuf at 128^2 (R16) also lost: LDS 68K -> 2 blocks/CU.
//  - spill sentinel: WRITE_SIZE ~9.3 MB. Any growth = scratch churn
//    (R12: 90 MB at (256,4); R17: 172 MB at 512thr+acc[4][8]).
// ---------------------------------------------------------------------------
__global__ __launch_bounds__(256, 3) void ntxent_main(
        const __hip_bfloat16* __restrict__ fn,
        const float* __restrict__ pmask, const float* __restrict__ nmask,
        float* __restrict__ negG, float* __restrict__ sG,
        float* __restrict__ pG) {
    __shared__ __align__(16) char smem[53248];   // fn 16K + 9 mask slots 36K
    __hip_bfloat16* Is = (__hip_bfloat16*)smem;             // [128*32] bf16
    __hip_bfloat16* Js = Is + 128 * 32;
    char* maskLds = smem + 16384;                           // 9 x 4096
    float* T = (float*)smem;                                // mirror transpose alias

    const int t = threadIdx.x;
    const int lane = t & 63;
    const int wv = t >> 6;
    const int wm = wv & 1;           // wave's j-half
    const int wn = wv >> 1;          // wave's i-half
    const int q  = lane >> 4;
    const int cl = lane & 15;

    // XCD-chunked swizzle (2080 = 8*260, bijective)
    const int bt0 = blockIdx.x;
    const int bt = (bt0 & 7) * 260 + (bt0 >> 3);

    // triangular decode: block bt -> (c, r) with c <= r
    int r = (int)((sqrtf(8.0f * (float)bt + 1.0f) - 1.0f) * 0.5f);
    while ((r + 1) * (r + 2) / 2 <= bt) ++r;
    while (r * (r + 1) / 2 > bt) --r;
    const int c = bt - r * (r + 1) / 2;
    const int rowBase = c * 128;     // i-tile
    const int colBase = r * 128;     // j-tile
    const bool offDiag = (c != r);

    const int rdSw = ((q ^ ((cl >> 1) & 3)) << 4);

    // slab DMA per-thread constants: row in slab, source-swizzled chunk
    const int sRow = t >> 5;                        // 0..7
    const int sChunk = (t & 31) ^ (sRow & 7);       // source chunk (pre-swizzled)

    floatx4 acc[4][4];            // [mf (j)][nf (i)]
#pragma unroll
    for (int mf = 0; mf < 4; ++mf)
#pragma unroll
        for (int nf = 0; nf < 4; ++nf)
            acc[mf][nf] = (floatx4){0.f, 0.f, 0.f, 0.f};

    // packed mask words: direct per nf, mirror per st; bits [15:0]=pos [31:16]=neg
    unsigned int dw[4] = {0u, 0u, 0u, 0u};
    unsigned int mw[4] = {0u, 0u, 0u, 0u};

    // slab issue: s in [0,64): side=s>>5 (0 direct,1 mirror), rg=(s&31)>>1, isN=s&1
    auto issue_slab = [&](int s) {
        const int slot = s % 9;
        const int side = s >> 5;
        const int rg   = (s & 31) >> 1;
        const float* mp = (s & 1) ? nmask : pmask;
        const int rowG = (side ? colBase : rowBase) + rg * 8 + sRow;
        const int colG = (side ? rowBase : colBase) + sChunk * 4;
        const float* src = mp + (size_t)rowG * NROWS + colG;
        __builtin_amdgcn_global_load_lds(
            (const __attribute__((address_space(1))) void*)src,
            (__attribute__((address_space(3))) void*)(maskLds + slot * 4096 + t * 16),
            16, 0, 0);
    };

    // pack: nibble = m0+2m1+4m2+8m3 (exact for 0/1); word = sum 16^i * nib_i
    auto pack_slab = [&](int s) {
        const int slot = s % 9;
        const int side = s >> 5;
        const int rg   = (s & 31) >> 1;
        const int sh   = (s & 1) ? 16 : 0;
        if (side == 0) {
            if (wn == (rg >> 3) && (cl >> 3) == (rg & 1)) {
                const int nf = (rg >> 1) & 3;
                const int rl = cl & 7;
                const char* base = maskLds + slot * 4096 + rl * 512;
                float word = 0.f;
#pragma unroll
                for (int mf = 3; mf >= 0; --mf) {
                    const int pos = (wm * 16 + mf * 4 + q) ^ rl;
                    const f4 m = *(const f4*)(base + pos * 16);
                    float nib = fmaf(2.f, m[1], m[0]) + fmaf(8.f, m[3], 4.f * m[2]);
                    word = fmaf(word, 16.f, nib);
                }
                dw[nf] |= ((unsigned int)word) << sh;
            }
        } else if (offDiag) {
            if (wv == (rg & 3)) {
                const int st = rg >> 2;
                const int rl = (t >> 3) & 7;
                const int h  = t & 7;
                const char* base = maskLds + slot * 4096 + rl * 512;
                float word = 0.f;
#pragma unroll
                for (int u = 3; u >= 0; --u) {
                    const int pos = (h * 4 + u) ^ rl;
                    const f4 m = *(const f4*)(base + pos * 16);
                    float nib = fmaf(2.f, m[1], m[0]) + fmaf(8.f, m[3], 4.f * m[2]);
                    word = fmaf(word, 16.f, nib);
                }
                mw[st] |= ((unsigned int)word) << sh;
            }
        }
    };

    // prologue: slabs for iters 0 and 1 issued; drain m(0), keep m(1) in flight
    issue_slab(0); issue_slab(1); issue_slab(2);
    issue_slab(3); issue_slab(4); issue_slab(5);
    asm volatile("s_waitcnt vmcnt(3)" ::: "memory");

#pragma unroll
    for (int kt = 0; kt < 24; ++kt) {
        const int k0 = kt * 32;
        // previous iter's LDS readers (fragments + pack) done before DMA overwrites
        asm volatile("s_waitcnt lgkmcnt(0)\n\ts_barrier" ::: "memory");

        // ---- fn staging (L2/L3-resident), 4 instrs ----
#pragma unroll
        for (int it = 0; it < 2; ++it) {
            const int s = it * 256 + t;              // 16B slot 0..511
            const int rr = s >> 2;
            const int cg = (s & 3) ^ ((rr >> 1) & 3); // swizzled src chunk
            const __hip_bfloat16* ga = fn + (size_t)(rowBase + rr) * DDIM + k0 + cg * 8;
            const __hip_bfloat16* gb = fn + (size_t)(colBase + rr) * DDIM + k0 + cg * 8;
            __builtin_amdgcn_global_load_lds(
                (const __attribute__((address_space(1))) void*)ga,
                (__attribute__((address_space(3))) void*)((char*)Is + s * 16), 16, 0, 0);
            __builtin_amdgcn_global_load_lds(
                (const __attribute__((address_space(1))) void*)gb,
                (__attribute__((address_space(3))) void*)((char*)Js + s * 16), 16, 0, 0);
        }

        // ---- mask prefetch for iter kt+2 (after fn -> fn is older in queue) ----
#pragma unroll
        for (int gl = 0; gl < 3; ++gl) {
            const int s = 3 * (kt + 2) + gl;
            if (s <= 63) issue_slab(s);
        }

        // ---- pack this iter's slabs IN THE DMA SHADOW (drained at wait(kt-1)) --
#pragma unroll
        for (int gl = 0; gl < 3; ++gl) {
            const int s = 3 * kt + gl;
            if (s <= 63) pack_slab(s);
        }

        // drain m(kt+1)+fn(kt); keep m(kt+2) in flight across the barrier
        if (kt <= 18)      asm volatile("s_waitcnt vmcnt(3)\n\ts_barrier" ::: "memory");
        else if (kt == 19) asm volatile("s_waitcnt vmcnt(1)\n\ts_barrier" ::: "memory");
        else               asm volatile("s_waitcnt vmcnt(0)\n\ts_barrier" ::: "memory");

        // ---- MFMA compute: per-mf jf load (reduced live registers) ----
        short8 if_[4];
#pragma unroll
        for (int nf = 0; nf < 4; ++nf) {
            const int rr = wn * 64 + nf * 16 + cl;
            if_[nf] = *(const short8*)((const char*)Is + rr * 64 + rdSw);
        }
#pragma unroll
        for (int mf = 0; mf < 4; ++mf) {
            const int rr = wm * 64 + mf * 16 + cl;
            const short8 jf = *(const short8*)((const char*)Js + rr * 64 + rdSw);
#pragma unroll
            for (int nf = 0; nf < 4; ++nf)
                acc[mf][nf] = __builtin_amdgcn_mfma_f32_16x16x32_bf16(
                    jf, if_[nf], acc[mf][nf], 0, 0, 0);
        }
    }

    // ---- direct epilogue (rows i, mask[i][j]) -- masks from dw bits ----
    const int col64 = colBase + wm * 64;
    const int jb0 = col64 + q * 4;
#pragma unroll
    for (int nf = 0; nf < 4; ++nf) {
        const int grow = rowBase + wn * 64 + nf * 16 + cl;
        const unsigned int w = dw[nf];
        float aN = 0.f, aS = 0.f, aP = 0.f;
#pragma unroll
        for (int mf = 0; mf < 4; ++mf) {
            const int jbase = jb0 + mf * 16;
#pragma unroll
            for (int reg = 0; reg < 4; ++reg) {
                const int b = mf * 4 + reg;
                float pmv = ((w >> b) & 1u) ? 1.0f : 0.0f;
                float nmv = ((w >> (16 + b)) & 1u) ? 1.0f : 0.0f;
                if (grow == jbase + reg) { pmv = 0.f; nmv = 0.f; }  // diagonal
                float v = acc[mf][nf][reg];
                float e = __builtin_amdgcn_exp2f(v * 14.4269504089f); // e^(10v)
                aN = fmaf(nmv, e, aN);
                aS = fmaf(pmv, v, aS);       // raw acc units; x10 in final_k
                aP += pmv;
            }
        }
        aN += __shfl_xor(aN, 16, 64);  aN += __shfl_xor(aN, 32, 64);
        aS += __shfl_xor(aS, 16, 64);  aS += __shfl_xor(aS, 32, 64);
        aP += __shfl_xor(aP, 16, 64);  aP += __shfl_xor(aP, 32, 64);
        if (q == 0) {
            atomicAdd(&negG[grow], aN);
            atomicAdd(&sG[grow],   aS);
            atomicAdd(&pG[grow],   aP);
        }
    }

    // ---- mirror epilogue (rows j, mask[j][i]) -- off-diagonal blocks only --
    if (offDiag) {
        const int jl2 = t >> 3;              // 0..31: strip-local j row
        const int iseg = (t & 7) * 16;       // 16-float i segment
#pragma unroll
        for (int st = 0; st < 4; ++st) {
            __syncthreads();                 // strip buffer free
            if (wm == (st >> 1)) {           // waves owning this strip's j's
#pragma unroll
                for (int m2 = 0; m2 < 2; ++m2) {
                    const int mf = (st & 1) * 2 + m2;
#pragma unroll
                    for (int nf = 0; nf < 4; ++nf) {
                        const int i = wn * 64 + nf * 16 + cl;
#pragma unroll
                        for (int reg = 0; reg < 4; ++reg) {
                            const int jl = m2 * 16 + q * 4 + reg;
                            T[jl * TSTRIDE + i] = acc[mf][nf][reg];
                        }
                    }
                }
            }
            __syncthreads();
            const int jg = colBase + st * 32 + jl2;
            const unsigned int w = mw[st];
            const f4* tv = (const f4*)(T + jl2 * TSTRIDE + iseg);
            float aN = 0.f, aS = 0.f, aP = 0.f;
#pragma unroll
            for (int u = 0; u < 4; ++u) {
                f4 v4 = tv[u];
#pragma unroll
                for (int e = 0; e < 4; ++e) {
                    const int b = u * 4 + e;
                    float v = v4[e];
                    float pmv = ((w >> b) & 1u) ? 1.0f : 0.0f;
                    float nmv = ((w >> (16 + b)) & 1u) ? 1.0f : 0.0f;
                    float ex = __builtin_amdgcn_exp2f(v * 14.4269504089f);
                    aN = fmaf(nmv, ex, aN);
                    aS = fmaf(pmv, v, aS);
                    aP += pmv;
                }
            }
            aN += __shfl_xor(aN, 1, 64); aN += __shfl_xor(aN, 2, 64); aN += __shfl_xor(aN, 4, 64);
            aS += __shfl_xor(aS, 1, 64); aS += __shfl_xor(aS, 2, 64); aS += __shfl_xor(aS, 4, 64);
            aP += __shfl_xor(aP, 1, 64); aP += __shfl_xor(aP, 2, 64); aP += __shfl_xor(aP, 4, 64);
            if ((t & 7) == 0) {
                atomicAdd(&negG[jg], aN);
                atomicAdd(&sG[jg],   aS);
                atomicAdd(&pG[jg],   aP);
            }
        }
    }
}

// ---------------------------------------------------------------------------
// Kernel 3: per-row loss assembly + mean
// loss_i = (P*log(neg) - 10*S_raw)/P (P>0 else 0);  out = mean
// ---------------------------------------------------------------------------
__global__ __launch_bounds__(1024) void final_k(const float* __restrict__ negG,
        const float* __restrict__ sG, const float* __restrict__ pG,
        float* __restrict__ out) {
    const int t = threadIdx.x;
    float sum = 0.f;
    for (int i = t; i < NROWS; i += 1024) {
        float P = pG[i];
        if (P > 0.f) {
            sum += (P * logf(negG[i]) - 10.0f * sG[i]) / P;
        }
    }
#pragma unroll
    for (int m = 32; m; m >>= 1) sum += __shfl_xor(sum, m, 64);
    __shared__ float wsum[16];
    if ((t & 63) == 0) wsum[t >> 6] = sum;
    __syncthreads();
    if (t < 16) {
        float v = wsum[t];
#pragma unroll
        for (int m = 8; m; m >>= 1) v += __shfl_xor(v, m, 16);
        if (t == 0) out[0] = v / (float)NROWS;
    }
}

// ---------------------------------------------------------------------------
extern "C" void kernel_launch(void* const* d_in, const int* in_sizes, int n_in,
                              void* d_out, int out_size, void* d_ws, size_t ws_size,
                              hipStream_t stream) {
    const float* feat  = (const float*)d_in[0];
    const float* pmask = (const float*)d_in[1];
    const float* nmask = (const float*)d_in[2];
    float* out = (float*)d_out;

    char* ws = (char*)d_ws;
    __hip_bfloat16* fn = (__hip_bfloat16*)ws;                    // 12,582,912 B
    float* negG = (float*)(ws + 12582912);
    float* sG = negG + NROWS;
    float* pG = sG + NROWS;

    // zero all three row accumulators (ws is re-poisoned before every launch)
    hipMemsetAsync(negG, 0, 3 * NROWS * sizeof(float), stream);

    normalize_k<<<NROWS, 256, 0, stream>>>(feat, fn);

    ntxent_main<<<2080, 256, 0, stream>>>(fn, pmask, nmask, negG, sG, pG);

    final_k<<<1, 1024, 0, stream>>>(negG, sG, pG, out);
}